// Round 9
// baseline (211.565 us; speedup 1.0000x reference)
//
#include <hip/hip_runtime.h>
#include <math.h>

#define D_   512
#define H_   4
#define KC   128
#define T_   1024
#define B_   4
#define NEG_ -10000.0f

typedef short bf16x8 __attribute__((ext_vector_type(8)));
typedef float f32x4  __attribute__((ext_vector_type(4)));

__device__ __forceinline__ ushort f2b_rne(float x) {
    unsigned u = __float_as_uint(x);
    u += 0x7fffu + ((u >> 16) & 1u);
    return (ushort)(u >> 16);
}
__device__ __forceinline__ unsigned pk2(float a, float b) {
    return (unsigned)f2b_rne(a) | ((unsigned)f2b_rne(b) << 16);
}
__device__ __forceinline__ float b2f_lo(unsigned u) { return __uint_as_float(u << 16); }
__device__ __forceinline__ float b2f_hi(unsigned u) { return __uint_as_float(u & 0xffff0000u); }

#define PLDA 40   // 32 k-elems + 8 pad

// ---------------------------------------------------------------------------
// Fused q/k/v projection GEMM, fp32 -> bf16 inline. Tile 128x64, BK=32,
// grid (32, 8, 3) = 768 blocks (3/CU). Wave tile 64x32 (4x2 MFMA).
// ---------------------------------------------------------------------------
__global__ __launch_bounds__(256) void proj_gemm(const float* __restrict__ x,
                                                 const float* __restrict__ cc,
                                                 const float* __restrict__ Wq,
                                                 const float* __restrict__ Wk,
                                                 const float* __restrict__ Wv,
                                                 const float* __restrict__ bq,
                                                 const float* __restrict__ bk,
                                                 const float* __restrict__ bv,
                                                 ushort* __restrict__ qb,
                                                 ushort* __restrict__ kb,
                                                 ushort* __restrict__ vtb)
{
    __shared__ __align__(16) ushort As[128 * PLDA];   // 10 KB
    __shared__ __align__(16) ushort Bs[64 * PLDA];    //  5 KB

    const int which = blockIdx.z;
    const float* A    = (which == 0) ? x  : cc;
    const float* W    = (which == 0) ? Wq : (which == 1) ? Wk : Wv;
    const float* bias = (which == 0) ? bq : (which == 1) ? bk : bv;

    const int m0 = blockIdx.x * 128;
    const int n0 = blockIdx.y * 64;
    const int tid = threadIdx.x;
    const int lane = tid & 63;
    const int wid  = tid >> 6;
    const int wm = (wid >> 1) * 64;
    const int wn = (wid & 1) * 32;
    const int c_   = lane & 15;
    const int quad = lane >> 4;

    const int srow  = tid >> 1;          // 0..127
    const int shalf = (tid & 1) * 16;
    const int srB   = tid >> 2;          // 0..63
    const int kb8   = (tid & 3) * 8;
    const float* ga = A + (size_t)(m0 + srow) * D_ + shalf;
    const float* gw = W + (size_t)(n0 + srB) * D_ + kb8;

    f32x4 acc[4][2] = {};
    float4 ar[4], wr[2];

#pragma unroll
    for (int p = 0; p < 4; p++) ar[p] = *(const float4*)(ga + p * 4);
#pragma unroll
    for (int p = 0; p < 2; p++) wr[p] = *(const float4*)(gw + p * 4);

    for (int it = 0; it < 16; it++) {
        __syncthreads();
        uint4 ua, ub;
        ua.x = pk2(ar[0].x, ar[0].y); ua.y = pk2(ar[0].z, ar[0].w);
        ua.z = pk2(ar[1].x, ar[1].y); ua.w = pk2(ar[1].z, ar[1].w);
        ub.x = pk2(ar[2].x, ar[2].y); ub.y = pk2(ar[2].z, ar[2].w);
        ub.z = pk2(ar[3].x, ar[3].y); ub.w = pk2(ar[3].z, ar[3].w);
        *(uint4*)(As + srow * PLDA + shalf)     = ua;
        *(uint4*)(As + srow * PLDA + shalf + 8) = ub;
        uint4 uw;
        uw.x = pk2(wr[0].x, wr[0].y); uw.y = pk2(wr[0].z, wr[0].w);
        uw.z = pk2(wr[1].x, wr[1].y); uw.w = pk2(wr[1].z, wr[1].w);
        *(uint4*)(Bs + srB * PLDA + kb8) = uw;
        __syncthreads();

        if (it < 15) {
            const int k0 = (it + 1) * 32;
#pragma unroll
            for (int p = 0; p < 4; p++) ar[p] = *(const float4*)(ga + k0 + p * 4);
#pragma unroll
            for (int p = 0; p < 2; p++) wr[p] = *(const float4*)(gw + k0 + p * 4);
        }

        bf16x8 af[4], bf[2];
#pragma unroll
        for (int mt = 0; mt < 4; mt++)
            af[mt] = *(const bf16x8*)(As + (wm + mt * 16 + c_) * PLDA + quad * 8);
#pragma unroll
        for (int nt = 0; nt < 2; nt++)
            bf[nt] = *(const bf16x8*)(Bs + (wn + nt * 16 + c_) * PLDA + quad * 8);
#pragma unroll
        for (int mt = 0; mt < 4; mt++)
#pragma unroll
            for (int nt = 0; nt < 2; nt++)
                acc[mt][nt] = __builtin_amdgcn_mfma_f32_16x16x32_bf16(
                    af[mt], bf[nt], acc[mt][nt], 0, 0, 0);
    }

#pragma unroll
    for (int mt = 0; mt < 4; mt++)
#pragma unroll
        for (int nt = 0; nt < 2; nt++) {
            const int n = n0 + wn + nt * 16 + c_;
            const float bn = bias[n];
            const int mb = m0 + wm + mt * 16 + quad * 4;
            const int b = mb >> 10;
            const int h = n >> 7, kc = n & (KC - 1);
            if (which == 2) {
                const int t0 = mb & (T_ - 1);
                ushort4 pk;
                pk.x = f2b_rne(acc[mt][nt][0] + bn);
                pk.y = f2b_rne(acc[mt][nt][1] + bn);
                pk.z = f2b_rne(acc[mt][nt][2] + bn);
                pk.w = f2b_rne(acc[mt][nt][3] + bn);
                *(ushort4*)(vtb + ((size_t)((b * H_ + h) * KC + kc)) * T_ + t0) = pk;
            } else {
                ushort* dst = (which == 0) ? qb : kb;
#pragma unroll
                for (int r = 0; r < 4; r++) {
                    const int m = mb + r;
                    const int t = m & (T_ - 1);
                    dst[((size_t)((b * H_ + h) * T_ + t)) * KC + kc] =
                        f2b_rne(acc[mt][nt][r] + bn);
                }
            }
        }
}

// ---------------------------------------------------------------------------
// Output GEMM: out = ab(bf16) * Wo^T + bo (fp32 out). Tile 64x64, BK=32,
// grid (64, 8) = 512 blocks (2/CU). Wave tile 32x32 (2x2 MFMA).
// ---------------------------------------------------------------------------
__global__ __launch_bounds__(256) void out_gemm(const ushort* __restrict__ ab,
                                                const float* __restrict__ Wo,
                                                const float* __restrict__ bo,
                                                float* __restrict__ out)
{
    __shared__ __align__(16) ushort As[64 * PLDA];
    __shared__ __align__(16) ushort Bs[64 * PLDA];

    const int m0 = blockIdx.x * 64;
    const int n0 = blockIdx.y * 64;
    const int tid = threadIdx.x;
    const int lane = tid & 63;
    const int wid  = tid >> 6;
    const int wm = (wid >> 1) * 32;
    const int wn = (wid & 1) * 32;
    const int c_   = lane & 15;
    const int quad = lane >> 4;

    const int srA = tid >> 2;            // 0..63
    const int skA = (tid & 3) * 8;
    const ushort* ga = ab + (size_t)(m0 + srA) * D_ + skA;
    const float*  gw = Wo + (size_t)(n0 + srA) * D_ + skA;

    f32x4 acc[2][2] = {};
    uint4 areg;
    float4 wr[2];

    areg = *(const uint4*)ga;
#pragma unroll
    for (int p = 0; p < 2; p++) wr[p] = *(const float4*)(gw + p * 4);

    for (int it = 0; it < 16; it++) {
        __syncthreads();
        *(uint4*)(As + srA * PLDA + skA) = areg;
        uint4 uw;
        uw.x = pk2(wr[0].x, wr[0].y); uw.y = pk2(wr[0].z, wr[0].w);
        uw.z = pk2(wr[1].x, wr[1].y); uw.w = pk2(wr[1].z, wr[1].w);
        *(uint4*)(Bs + srA * PLDA + skA) = uw;
        __syncthreads();

        if (it < 15) {
            const int k0 = (it + 1) * 32;
            areg = *(const uint4*)(ga + k0);
#pragma unroll
            for (int p = 0; p < 2; p++) wr[p] = *(const float4*)(gw + k0 + p * 4);
        }

        bf16x8 af[2], bf[2];
#pragma unroll
        for (int mt = 0; mt < 2; mt++)
            af[mt] = *(const bf16x8*)(As + (wm + mt * 16 + c_) * PLDA + quad * 8);
#pragma unroll
        for (int nt = 0; nt < 2; nt++)
            bf[nt] = *(const bf16x8*)(Bs + (wn + nt * 16 + c_) * PLDA + quad * 8);
#pragma unroll
        for (int mt = 0; mt < 2; mt++)
#pragma unroll
            for (int nt = 0; nt < 2; nt++)
                acc[mt][nt] = __builtin_amdgcn_mfma_f32_16x16x32_bf16(
                    af[mt], bf[nt], acc[mt][nt], 0, 0, 0);
    }

#pragma unroll
    for (int mt = 0; mt < 2; mt++)
#pragma unroll
        for (int nt = 0; nt < 2; nt++) {
            const int n = n0 + wn + nt * 16 + c_;
            const float bn = bo[n];
            const int mb = m0 + wm + mt * 16 + quad * 4;
#pragma unroll
            for (int r = 0; r < 4; r++)
                out[(size_t)(mb + r) * D_ + n] = acc[mt][nt][r] + bn;
        }
}

// ---------------------------------------------------------------------------
// Split-band MFMA flash attention.
// Grid 1024 blocks; block = (bh, 16-row Q group). The 4 waves split the
// band tiles strided (t = wid, wid+4, ...), each with private online-softmax
// state; end-of-kernel LDS merge (flash split-K combine) + rel-v epilogue.
// K/V/Q fragments direct from global (L2-resident; XCD swizzle 2 bh/XCD).
// LDS ~51 KB -> 3 blocks/CU -> 3 waves/SIMD (vs 1 in R8).
// ---------------------------------------------------------------------------
#define OPS 132   // Opart row stride (floats): 128 + 4 pad

__global__ __launch_bounds__(256, 3) void attn_mfma(const ushort* __restrict__ qg,
                                                    const ushort* __restrict__ kg,
                                                    const ushort* __restrict__ vtg,
                                                    const float* __restrict__ mask,
                                                    const float* __restrict__ relk,
                                                    const float* __restrict__ relv,
                                                    ushort* __restrict__ outp)
{
    const int blk = blockIdx.x;
    const int bh  = (blk & 7) * 2 + (blk >> 9);   // 2 bh per XCD
    const int i0  = ((blk >> 3) & 63) * 16;       // 16-row Q group
    const int b   = bh >> 2;
    const int h   = bh & 3;
    const int tid  = threadIdx.x;
    const int lane = tid & 63;
    const int wid  = tid >> 6;
    const int c_   = lane & 15;
    const int quad = lane >> 4;

    __shared__ float lg[257];                       // 1 KB
    __shared__ float relbuf[9 * KC];                // 4.5 KB (relk, then relv)
    __shared__ float rlog[16 * 9];                  // 576 B (shared by waves)
    __shared__ float pdiag[4][16 * 9];              // 2.25 KB
    __shared__ float mpart[4][16], lpart[4][16];    // 512 B
    __shared__ __align__(16) ushort Ps[4][16 * 72]; // 9 KB
    __shared__ __align__(16) float Opart[4][16 * OPS]; // 33 KB

    const float scale = 0.08838834764831845f;  // 1/sqrt(128)

    for (int e = tid; e < 257; e += 256) lg[e] = log1pf((float)e);
    for (int e = tid; e < 9 * KC; e += 256) relbuf[e] = relk[e];
    {
        float* pd = &pdiag[wid][0];
        for (int e = lane; e < 144; e += 64) pd[e] = 0.f;
    }
    __syncthreads();   // barrier 1: relbuf=relk, lg ready

    // ---- rel-k logits (wave 0 only; rows shared by all waves) ----
    if (wid == 0) {
        const int r   = lane >> 2;   // 0..15
        const int kq4 = lane & 3;
        const ushort* qrow = qg + (size_t)(bh * T_ + i0 + r) * KC + kq4 * 32;
        float sacc[9];
#pragma unroll
        for (int d = 0; d < 9; d++) sacc[d] = 0.f;
#pragma unroll
        for (int kk = 0; kk < 32; kk += 2) {
            const unsigned u = *(const unsigned*)(qrow + kk);
            const float q0 = b2f_lo(u), q1 = b2f_hi(u);
            const int kbase = kq4 * 32 + kk;
#pragma unroll
            for (int d = 0; d < 9; d++)
                sacc[d] += q0 * relbuf[d * KC + kbase] + q1 * relbuf[d * KC + kbase + 1];
        }
#pragma unroll
        for (int d = 0; d < 9; d++) {
            sacc[d] += __shfl_xor(sacc[d], 1);
            sacc[d] += __shfl_xor(sacc[d], 2);
            if (kq4 == 0) rlog[r * 9 + d] = sacc[d] * scale;
        }
    }
    __syncthreads();   // barrier 2: rlog ready
    // restage relbuf with relv (read only after barrier 3)
    for (int e = tid; e < 9 * KC; e += 256) relbuf[e] = relv[e];

    // ---- Q A-fragments direct from global ----
    bf16x8 aqr[4];
#pragma unroll
    for (int ks = 0; ks < 4; ks++)
        aqr[ks] = *(const bf16x8*)(qg + (size_t)(bh * T_ + i0 + c_) * KC + (ks * 4 + quad) * 8);

    float rmv[4];
#pragma unroll
    for (int r4 = 0; r4 < 4; r4++) rmv[r4] = mask[b * T_ + i0 + quad * 4 + r4];

    float m_run[4], l_run[4];
    f32x4 acco[8] = {};
#pragma unroll
    for (int r4 = 0; r4 < 4; r4++) { m_run[r4] = -1e30f; l_run[r4] = 0.f; }

    const int cs0    = (i0 - 256 > 0) ? (i0 - 256) : 0;
    const int cstart = cs0 & ~63;
    const int cend   = (i0 + 16 + 256 < T_) ? (i0 + 16 + 256) : T_;
    const int ntl    = (cend - cstart + 63) >> 6;   // 5..9 -> every wave gets >=1

    ushort* Psw = &Ps[wid][0];
    float*  pdw = &pdiag[wid][0];

    for (int t = wid; t < ntl; t += 4) {
        const int j0 = cstart + t * 64;

        // ---- S B-frags direct from global K ----
        bf16x8 kf[4][4];
#pragma unroll
        for (int ct = 0; ct < 4; ct++)
#pragma unroll
            for (int ks = 0; ks < 4; ks++)
                kf[ct][ks] = *(const bf16x8*)(kg +
                    (size_t)(bh * T_ + j0 + ct * 16 + c_) * KC + (ks * 4 + quad) * 8);

        f32x4 accs[4] = {};
#pragma unroll
        for (int ks = 0; ks < 4; ks++)
#pragma unroll
            for (int ct = 0; ct < 4; ct++)
                accs[ct] = __builtin_amdgcn_mfma_f32_16x16x32_bf16(
                    aqr[ks], kf[ct][ks], accs[ct], 0, 0, 0);

        // ---- online softmax on C-layout fragments (intra-wave) ----
        float mskv[4];
#pragma unroll
        for (int ct = 0; ct < 4; ct++) mskv[ct] = mask[b * T_ + j0 + ct * 16 + c_];

        float alpha4[4];
#pragma unroll
        for (int r4 = 0; r4 < 4; r4++) {
            const int row = quad * 4 + r4;       // 0..15
            const float rm = rmv[r4];
            const int dj = j0 - i0 + c_ - row;
            float sv[4];
            float mt = -3e38f;
#pragma unroll
            for (int ct = 0; ct < 4; ct++) {
                const int d = dj + ct * 16;
                const unsigned ad = (unsigned)((d < 0) ? -d : d);
                float s;
                if (rm != 0.f && mskv[ct] != 0.f && ad <= 256u) {
                    s = accs[ct][r4] * scale - lg[ad];
                    const unsigned dw = (unsigned)(d + 4);
                    if (dw <= 8u) s += rlog[row * 9 + dw];
                } else {
                    s = NEG_;
                }
                sv[ct] = s;
                mt = fmaxf(mt, s);
            }
            mt = fmaxf(mt, __shfl_xor(mt, 1));
            mt = fmaxf(mt, __shfl_xor(mt, 2));
            mt = fmaxf(mt, __shfl_xor(mt, 4));
            mt = fmaxf(mt, __shfl_xor(mt, 8));
            const float mnew = fmaxf(m_run[r4], mt);
            const float al = __expf(m_run[r4] - mnew);
            alpha4[r4] = al;
            m_run[r4] = mnew;

            float lt = 0.f;
#pragma unroll
            for (int ct = 0; ct < 4; ct++) {
                const float p = __expf(sv[ct] - mnew);
                sv[ct] = p;
                lt += p;
                Psw[row * 72 + ct * 16 + c_] = f2b_rne(p);
            }
            lt += __shfl_xor(lt, 1);
            lt += __shfl_xor(lt, 2);
            lt += __shfl_xor(lt, 4);
            lt += __shfl_xor(lt, 8);
            l_run[r4] = l_run[r4] * al + lt;

            if (c_ == 0) {
#pragma unroll
                for (int dd = 0; dd < 9; dd++) pdw[row * 9 + dd] *= al;
            }
#pragma unroll
            for (int ct = 0; ct < 4; ct++) {
                const int d = dj + ct * 16;
                const unsigned dw = (unsigned)(d + 4);
                if (dw <= 8u) pdw[row * 9 + dw] += sv[ct];
            }
        }

        // ---- PV: V^T B-frags direct from global; P from wave LDS ----
        bf16x8 vf[2][8];
#pragma unroll
        for (int nt = 0; nt < 8; nt++)
#pragma unroll
            for (int kt = 0; kt < 2; kt++)
                vf[kt][nt] = *(const bf16x8*)(vtg +
                    (size_t)(bh * KC + nt * 16 + c_) * T_ + j0 + (kt * 4 + quad) * 8);

#pragma unroll
        for (int nt = 0; nt < 8; nt++)
#pragma unroll
            for (int r4 = 0; r4 < 4; r4++) acco[nt][r4] *= alpha4[r4];

        bf16x8 ap[2];
#pragma unroll
        for (int kt = 0; kt < 2; kt++)
            ap[kt] = *(const bf16x8*)(Psw + c_ * 72 + (kt * 4 + quad) * 8);
#pragma unroll
        for (int kt = 0; kt < 2; kt++)
#pragma unroll
            for (int nt = 0; nt < 8; nt++)
                acco[nt] = __builtin_amdgcn_mfma_f32_16x16x32_bf16(
                    ap[kt], vf[kt][nt], acco[nt], 0, 0, 0);
    }

    // ---- publish per-wave partials ----
#pragma unroll
    for (int r4 = 0; r4 < 4; r4++) {
        const int row = quad * 4 + r4;
        if (c_ == 0) { mpart[wid][row] = m_run[r4]; lpart[wid][row] = l_run[r4]; }
#pragma unroll
        for (int nt = 0; nt < 8; nt++)
            Opart[wid][row * OPS + nt * 16 + c_] = acco[nt][r4];
    }
    __syncthreads();   // barrier 3: partials + relv ready

    // ---- merge (flash split-K combine) + rel-v + store ----
    {
        const int mrow = tid >> 4;          // 0..15
        const int col0 = (tid & 15) * 8;    // 8 channels per thread
        float ms = -3e38f;
#pragma unroll
        for (int w = 0; w < 4; w++) ms = fmaxf(ms, mpart[w][mrow]);
        float ew[4];
        float ls = 0.f;
#pragma unroll
        for (int w = 0; w < 4; w++) {
            ew[w] = __expf(mpart[w][mrow] - ms);
            ls += ew[w] * lpart[w][mrow];
        }
        float o[8];
#pragma unroll
        for (int c = 0; c < 8; c++) o[c] = 0.f;
#pragma unroll
        for (int w = 0; w < 4; w++) {
            const float4 oa = *(const float4*)&Opart[w][mrow * OPS + col0];
            const float4 ob = *(const float4*)&Opart[w][mrow * OPS + col0 + 4];
            o[0] += ew[w] * oa.x; o[1] += ew[w] * oa.y;
            o[2] += ew[w] * oa.z; o[3] += ew[w] * oa.w;
            o[4] += ew[w] * ob.x; o[5] += ew[w] * ob.y;
            o[6] += ew[w] * ob.z; o[7] += ew[w] * ob.w;
        }
        float pd[9];
#pragma unroll
        for (int d = 0; d < 9; d++) {
            float s = 0.f;
#pragma unroll
            for (int w = 0; w < 4; w++) s += ew[w] * pdiag[w][mrow * 9 + d];
            pd[d] = s;   // OOB diagonals are structurally 0 (never visited)
        }
        const float invl = 1.f / ls;
#pragma unroll
        for (int c = 0; c < 8; c++) {
            float v = o[c];
#pragma unroll
            for (int d = 0; d < 9; d++) v += pd[d] * relbuf[d * KC + col0 + c];
            o[c] = v * invl;
        }
        const int i = i0 + mrow;
        ushort* ob = outp + ((size_t)(b * T_ + i) * H_ + h) * KC + col0;
        uint4 w4;
        w4.x = pk2(o[0], o[1]); w4.y = pk2(o[2], o[3]);
        w4.z = pk2(o[4], o[5]); w4.w = pk2(o[6], o[7]);
        *(uint4*)ob = w4;
    }
}

// ---------------------------------------------------------------------------
extern "C" void kernel_launch(void* const* d_in, const int* in_sizes, int n_in,
                              void* d_out, int out_size, void* d_ws, size_t ws_size,
                              hipStream_t stream)
{
    const float* x    = (const float*)d_in[0];
    const float* c    = (const float*)d_in[1];
    const float* am   = (const float*)d_in[2];
    const float* Wq   = (const float*)d_in[3];
    const float* bq   = (const float*)d_in[4];
    const float* Wk   = (const float*)d_in[5];
    const float* bk   = (const float*)d_in[6];
    const float* Wv   = (const float*)d_in[7];
    const float* bv   = (const float*)d_in[8];
    const float* Wo   = (const float*)d_in[9];
    const float* bo   = (const float*)d_in[10];
    const float* relk = (const float*)d_in[11];
    const float* relv = (const float*)d_in[12];

    float* out = (float*)d_out;
    char* w8 = (char*)d_ws;
    ushort* qb  = (ushort*)(w8);
    ushort* kb  = (ushort*)(w8 + (4u << 20));
    ushort* vtb = (ushort*)(w8 + (8u << 20));   // [B,H,KC,T]
    ushort* ab  = (ushort*)(w8 + (12u << 20));

    proj_gemm<<<dim3(32, 8, 3), 256, 0, stream>>>(x, c, Wq, Wk, Wv, bq, bk, bv,
                                                  qb, kb, vtb);

    attn_mfma<<<1024, 256, 0, stream>>>(qb, kb, vtb, am, relk, relv, ab);

    out_gemm<<<dim3(64, 8), 256, 0, stream>>>(ab, Wo, bo, out);
}